// Round 3
// baseline (414.664 us; speedup 1.0000x reference)
//
#include <hip/hip_runtime.h>
#include <math.h>

#define AN 120000
#define BN 16
#define GN 32
#define BLK 256
#define NBX ((AN + BLK - 1) / BLK)      // 469 blocks along anchors
#define NBTOT (NBX * BN)                // 7504 blocks total

// d_ws layout:
//   rec:     [BN*GN][8] floats = 16384 B   {x, y, z, w, area/3, 0, 0, 0}
//   counter: int at byte 16384
//   partial: [4][BN][NBX] floats at byte 16448

__device__ __forceinline__ float sl1(float d) {
    float ad = fabsf(d);
    return ad < 1.0f ? 0.5f * d * d : ad - 0.5f;
}

// Prelude: pack GT records for scalar-load consumption; zero the ticket counter.
__global__ __launch_bounds__(512) void prelude(const float* __restrict__ gt_boxes,
                                               float* __restrict__ rec,
                                               int* __restrict__ counter) {
    const int t = threadIdx.x;              // 512 = BN*GN, one record per thread
    if (t == 0) *counter = 0;
    float4 box = *(const float4*)(gt_boxes + t * 4);
    float sg3 = (box.z - box.x) * (box.w - box.y) * (1.f / 3.f);
    float* r = rec + t * 8;
    r[0] = box.x; r[1] = box.y; r[2] = box.z; r[3] = box.w;
    r[4] = sg3;   r[5] = 0.f;   r[6] = 0.f;   r[7] = 0.f;
}

__global__ __launch_bounds__(256) void loss_main(
    const float* __restrict__ pred_cls,
    const float* __restrict__ pred_bbox,
    const float* __restrict__ pred_ldm,
    const float* __restrict__ anchors,
    const float* __restrict__ gt_boxes,
    const float* __restrict__ gt_ldm,
    const float* __restrict__ rec,
    float* __restrict__ partial,
    int* __restrict__ counter,
    float* __restrict__ out)
{
    const int b   = blockIdx.y;
    const int tid = threadIdx.x;
    const int a   = blockIdx.x * BLK + tid;
    const bool val = (a < AN);

    // Anchor in registers; invalid tail lanes get zeros (their pos is unused).
    float4 an4 = make_float4(0.f, 0.f, 0.f, 0.f);
    if (val) an4 = *(const float4*)(anchors + (size_t)a * 4);
    const float sa3 = (an4.z - an4.x) * (an4.w - an4.y) * (1.f / 3.f);

    // Hot loop: UNIFORM control flow + uniform addresses -> scalar loads (SGPRs).
    // Division-free test: IoU>=0.5  <=>  inter >= (sa+sg)/3. Single clamp on iw
    // suffices: iw<=0 -> inter=0 fails; iw>0,ih<0 -> inter<0 fails.
    const float* __restrict__ rb = rec + (size_t)b * GN * 8;
    bool pos = false;
    #pragma unroll 4
    for (int g = 0; g < GN; ++g) {
        const float gx  = rb[g * 8 + 0];
        const float gy  = rb[g * 8 + 1];
        const float gz  = rb[g * 8 + 2];
        const float gw  = rb[g * 8 + 3];
        const float sg3 = rb[g * 8 + 4];
        float iw = fmaxf(fminf(an4.z, gz) - fmaxf(an4.x, gx), 0.f);
        float ih = fminf(an4.w, gw) - fmaxf(an4.y, gy);
        float inter = iw * ih;
        pos = pos || (inter >= sa3 + sg3);
    }

    float ce = 0.f, np = 0.f, rl = 0.f, ll = 0.f;

    if (val) {
        // CE: stable lse = max + log(1 + exp(-|d|)) with hardware exp/log.
        float2 pc = *(const float2*)(pred_cls + ((size_t)b * AN + a) * 2);
        float d = pc.x - pc.y;
        float lse = fmaxf(pc.x, pc.y) + __logf(1.f + __expf(-fabsf(d)));
        ce = lse - (pos ? pc.y : pc.x);

        // Cold path (~0.03% of anchors): exact argmax via cross-multiplication.
        if (pos) {
            const float sa = (an4.z - an4.x) * (an4.w - an4.y);
            float bi = -1.f, bu = 1.f; int bg = 0;
            #pragma unroll 4
            for (int g = 0; g < GN; ++g) {
                float4 gb = *(const float4*)(gt_boxes + ((size_t)b * GN + g) * 4);
                float iw = fmaxf(fminf(an4.z, gb.z) - fmaxf(an4.x, gb.x), 0.f);
                float ih = fmaxf(fminf(an4.w, gb.w) - fmaxf(an4.y, gb.y), 0.f);
                float inter = iw * ih;
                float sg = (gb.z - gb.x) * (gb.w - gb.y);
                float uni = sa + sg - inter;
                bool upd = inter * bu > bi * uni;   // strict > keeps first max
                bi = upd ? inter : bi;
                bu = upd ? uni   : bu;
                bg = upd ? g     : bg;
            }
            np = 1.f;
            float4 gb = *(const float4*)(gt_boxes + ((size_t)b * GN + bg) * 4);
            float aw = an4.z - an4.x, ah = an4.w - an4.y;
            float acx = an4.x + 0.5f * aw, acy = an4.y + 0.5f * ah;
            float gw = gb.z - gb.x, gh = gb.w - gb.y;
            float gcx = gb.x + 0.5f * gw, gcy = gb.y + 0.5f * gh;
            float t0 = (gcx - acx) / aw;
            float t1 = (gcy - acy) / ah;
            float t2 = __logf(gw / aw);
            float t3 = __logf(gh / ah);
            const float4 pb = *(const float4*)(pred_bbox + ((size_t)b * AN + a) * 4);
            rl = sl1(pb.x - t0) + sl1(pb.y - t1) + sl1(pb.z - t2) + sl1(pb.w - t3);
            const float* pl = pred_ldm + ((size_t)b * AN + a) * 10;
            const float* gl = gt_ldm + ((size_t)b * GN + bg) * 10;
            float s = 0.f;
            #pragma unroll
            for (int j = 0; j < 10; ++j) s += sl1(pl[j] - gl[j]);
            ll = s;
        }
    }

    // Block reduction: wave shuffle then cross-wave via LDS.
    __shared__ float red[4][4];
    #pragma unroll
    for (int off = 32; off > 0; off >>= 1) {
        ce += __shfl_down(ce, off, 64);
        np += __shfl_down(np, off, 64);
        rl += __shfl_down(rl, off, 64);
        ll += __shfl_down(ll, off, 64);
    }
    const int lane = tid & 63, wid = tid >> 6;
    if (lane == 0) { red[0][wid] = ce; red[1][wid] = np; red[2][wid] = rl; red[3][wid] = ll; }
    __syncthreads();
    if (tid < 4) {
        float s = red[tid][0] + red[tid][1] + red[tid][2] + red[tid][3];
        partial[(size_t)tid * (BN * NBX) + (size_t)b * NBX + blockIdx.x] = s;
    }

    // Last-block finalize (ticket pattern; device-scope fences for cross-XCD).
    __shared__ int lastflag;
    __syncthreads();                       // partial stores complete block-wide
    if (tid == 0) {
        __threadfence();                   // release our partials to device scope
        int t = atomicAdd(counter, 1);
        lastflag = (t == NBTOT - 1) ? 1 : 0;
    }
    __syncthreads();
    if (!lastflag) return;
    __threadfence();                       // acquire all blocks' partials

    __shared__ float rowsum[64];
    const int row = tid >> 2, sub = tid & 3;   // 64 rows (q*16+b), 4 lanes each
    float s = 0.f;
    const float* p = partial + (size_t)row * NBX;
    for (int j = sub; j < NBX; j += 4) s += p[j];
    s += __shfl_down(s, 1, 64);
    s += __shfl_down(s, 2, 64);
    if (sub == 0) rowsum[row] = s;
    __syncthreads();

    if (tid == 0) {
        float cls = 0.f, reg = 0.f, ldm = 0.f;
        for (int bb = 0; bb < BN; ++bb) {
            cls += rowsum[0 * BN + bb] / (float)AN;
            float npv = rowsum[1 * BN + bb];
            float den = fmaxf(npv, 1.f);
            bool has = npv > 0.f;
            reg += has ? rowsum[2 * BN + bb] / (den * 4.f)  : 0.f;
            ldm += has ? rowsum[3 * BN + bb] / (den * 10.f) : 0.f;
        }
        cls /= (float)BN; reg /= (float)BN; ldm /= (float)BN;
        out[0] = cls + reg + ldm;
        out[1] = cls;
        out[2] = reg;
        out[3] = ldm;
    }
}

extern "C" void kernel_launch(void* const* d_in, const int* in_sizes, int n_in,
                              void* d_out, int out_size, void* d_ws, size_t ws_size,
                              hipStream_t stream) {
    const float* pred_cls  = (const float*)d_in[0];
    const float* pred_bbox = (const float*)d_in[1];
    const float* pred_ldm  = (const float*)d_in[2];
    const float* anchors   = (const float*)d_in[3];
    const float* gt_boxes  = (const float*)d_in[4];
    const float* gt_ldm    = (const float*)d_in[5];
    float* out = (float*)d_out;

    float* rec     = (float*)d_ws;                       // 16384 B
    int*   counter = (int*)((char*)d_ws + 16384);
    float* partial = (float*)((char*)d_ws + 16448);      // 4*16*469 floats

    prelude<<<1, 512, 0, stream>>>(gt_boxes, rec, counter);
    dim3 grid(NBX, BN);
    loss_main<<<grid, BLK, 0, stream>>>(pred_cls, pred_bbox, pred_ldm, anchors,
                                        gt_boxes, gt_ldm, rec, partial, counter, out);
}

// Round 7
// 412.926 us; speedup vs baseline: 1.0042x; 1.0042x over previous
//
#include <hip/hip_runtime.h>
#include <math.h>

#define AN 120000
#define BN 16
#define GN 32
#define BLK 256
#define NBX ((AN + BLK - 1) / BLK)   // 469
#define NBTOT (NBX * BN)             // 7504

typedef float f16v __attribute__((ext_vector_type(16)));

__device__ __forceinline__ float sl1(float d) {
    float ad = fabsf(d);
    return ad < 1.0f ? 0.5f * d * d : ad - 0.5f;
}

// ws layout: sg3buf [BN*GN] floats (2048 B) | counter int @ 2048 | partial @ 2112
__global__ __launch_bounds__(512) void prelude(const float* __restrict__ gt_boxes,
                                               float* __restrict__ sg3buf,
                                               int* __restrict__ counter) {
    const int t = threadIdx.x;          // 512 = BN*GN
    if (t == 0) *counter = 0;
    float4 box = *(const float4*)(gt_boxes + t * 4);
    sg3buf[t] = (box.z - box.x) * (box.w - box.y) * (1.f / 3.f);
}

__global__ __launch_bounds__(256) void loss_main(
    const float* __restrict__ pred_cls,
    const float* __restrict__ pred_bbox,
    const float* __restrict__ pred_ldm,
    const float* __restrict__ anchors,
    const float* __restrict__ gt_boxes,
    const float* __restrict__ gt_ldm,
    const float* __restrict__ sg3buf,
    float* __restrict__ partial,        // [4][BN][NBX]
    int* __restrict__ counter,
    float* __restrict__ out)
{
    __shared__ float4 gtb[GN];
    const int b   = blockIdx.y;
    const int tid = threadIdx.x;
    const int a   = blockIdx.x * BLK + tid;
    const bool val = (a < AN);

    if (tid < GN) gtb[tid] = *(const float4*)(gt_boxes + (b * GN + tid) * 4);

    // Anchor + pred_cls prefetch: VMEM latency overlaps the IoU loop.
    float4 an4 = make_float4(0.f, 0.f, 0.f, 0.f);
    if (val) an4 = *(const float4*)(anchors + (size_t)a * 4);
    float2 pc = make_float2(0.f, 0.f);
    if (val) pc = *(const float2*)(pred_cls + ((size_t)b * AN + a) * 2);

    const float sa3 = (an4.z - an4.x) * (an4.w - an4.y) * (1.f / 3.f);

    __syncthreads();

    // Per-g area/3 table -> SGPRs. Explicit s_load: wave-uniform by construction,
    // one-time ~200cy latency, frees the LDS pipe of 32 b32 reads per row.
    const float* sg3p = sg3buf + b * GN;   // uniform address
    f16v sA, sB;
    asm volatile("s_load_dwordx16 %0, %2, 0x0\n\t"
                 "s_load_dwordx16 %1, %2, 0x40\n\t"
                 "s_waitcnt lgkmcnt(0)"
                 : "=&s"(sA), "=&s"(sB)
                 : "s"(sg3p));

    // Hot loop: per g = 1 ds_read_b128 (imm offset) + ~10 VALU.
    // Test: IoU>=0.5  <=>  inter >= (sa+sg)/3. Single clamp on iw suffices:
    // iw<=0 -> inter<=0 fails (rhs>0); iw>0,ih<0 -> inter<0 fails.
    bool pos = false;
#define IOUT(G, SG3) {                                                      \
        const float4 gb = gtb[(G)];                                         \
        float iw = fmaxf(fminf(an4.z, gb.z) - fmaxf(an4.x, gb.x), 0.f);     \
        float ih = fminf(an4.w, gb.w) - fmaxf(an4.y, gb.y);                 \
        pos = pos | (iw * ih >= sa3 + (SG3)); }
    #pragma unroll
    for (int g = 0; g < 16; ++g) IOUT(g, sA[g]);
    #pragma unroll
    for (int g = 0; g < 16; ++g) IOUT(g + 16, sB[g]);
#undef IOUT

    float ce = 0.f, np = 0.f, rl = 0.f, ll = 0.f;

    if (val) {
        // CE: stable lse = max + log(1 + exp(-|d|)), hardware exp/log.
        float d = pc.x - pc.y;
        float lse = fmaxf(pc.x, pc.y) + __logf(1.f + __expf(-fabsf(d)));
        ce = lse - (pos ? pc.y : pc.x);

        // Cold path (~0.03% of anchors). Boxes re-read from LDS.
        if (pos) {
            const float sa = (an4.z - an4.x) * (an4.w - an4.y);
            float bi = -1.f, bu = 1.f; int bg = 0;
            #pragma unroll 8
            for (int g = 0; g < GN; ++g) {
                float4 gb = gtb[g];
                float iw = fmaxf(fminf(an4.z, gb.z) - fmaxf(an4.x, gb.x), 0.f);
                float ih = fmaxf(fminf(an4.w, gb.w) - fmaxf(an4.y, gb.y), 0.f);
                float inter = iw * ih;
                float sg = (gb.z - gb.x) * (gb.w - gb.y);
                float uni = sa + sg - inter;
                bool upd = inter * bu > bi * uni;   // strict > keeps first max
                bi = upd ? inter : bi;
                bu = upd ? uni   : bu;
                bg = upd ? g     : bg;
            }
            np = 1.f;
            float4 gb = gtb[bg];
            float aw = an4.z - an4.x, ah = an4.w - an4.y;
            float acx = an4.x + 0.5f * aw, acy = an4.y + 0.5f * ah;
            float gw = gb.z - gb.x, gh = gb.w - gb.y;
            float gcx = gb.x + 0.5f * gw, gcy = gb.y + 0.5f * gh;
            float t0 = (gcx - acx) / aw;
            float t1 = (gcy - acy) / ah;
            float t2 = __logf(gw / aw);
            float t3 = __logf(gh / ah);
            const float4 pb = *(const float4*)(pred_bbox + ((size_t)b * AN + a) * 4);
            rl = sl1(pb.x - t0) + sl1(pb.y - t1) + sl1(pb.z - t2) + sl1(pb.w - t3);
            const float* pl = pred_ldm + ((size_t)b * AN + a) * 10;
            const float* gl = gt_ldm + ((size_t)b * GN + bg) * 10;
            float s = 0.f;
            #pragma unroll
            for (int j = 0; j < 10; ++j) s += sl1(pl[j] - gl[j]);
            ll = s;
        }
    }

    // Block reduction: wave shuffle then cross-wave via LDS.
    __shared__ float red[4][4];
    #pragma unroll
    for (int off = 32; off > 0; off >>= 1) {
        ce += __shfl_down(ce, off, 64);
        np += __shfl_down(np, off, 64);
        rl += __shfl_down(rl, off, 64);
        ll += __shfl_down(ll, off, 64);
    }
    const int lane = tid & 63, wid = tid >> 6;
    if (lane == 0) { red[0][wid] = ce; red[1][wid] = np; red[2][wid] = rl; red[3][wid] = ll; }
    __syncthreads();
    if (tid < 4) {
        float s = red[tid][0] + red[tid][1] + red[tid][2] + red[tid][3];
        partial[(size_t)tid * (BN * NBX) + (size_t)b * NBX + blockIdx.x] = s;
    }

    // Last-block finalize (ticket pattern; device-scope fences for cross-XCD).
    __shared__ int lastflag;
    __syncthreads();
    if (tid == 0) {
        __threadfence();
        int t = atomicAdd(counter, 1);
        lastflag = (t == NBTOT - 1) ? 1 : 0;
    }
    __syncthreads();
    if (!lastflag) return;
    __threadfence();

    __shared__ float rowsum[64];
    const int row = tid >> 2, sub = tid & 3;
    float s = 0.f;
    const float* p = partial + (size_t)row * NBX;
    for (int j = sub; j < NBX; j += 4) s += p[j];
    s += __shfl_down(s, 1, 64);
    s += __shfl_down(s, 2, 64);
    if (sub == 0) rowsum[row] = s;
    __syncthreads();

    if (tid == 0) {
        float cls = 0.f, reg = 0.f, ldm = 0.f;
        for (int bb = 0; bb < BN; ++bb) {
            cls += rowsum[0 * BN + bb] / (float)AN;
            float npv = rowsum[1 * BN + bb];
            float den = fmaxf(npv, 1.f);
            bool has = npv > 0.f;
            reg += has ? rowsum[2 * BN + bb] / (den * 4.f)  : 0.f;
            ldm += has ? rowsum[3 * BN + bb] / (den * 10.f) : 0.f;
        }
        cls /= (float)BN; reg /= (float)BN; ldm /= (float)BN;
        out[0] = cls + reg + ldm;
        out[1] = cls;
        out[2] = reg;
        out[3] = ldm;
    }
}

extern "C" void kernel_launch(void* const* d_in, const int* in_sizes, int n_in,
                              void* d_out, int out_size, void* d_ws, size_t ws_size,
                              hipStream_t stream) {
    const float* pred_cls  = (const float*)d_in[0];
    const float* pred_bbox = (const float*)d_in[1];
    const float* pred_ldm  = (const float*)d_in[2];
    const float* anchors   = (const float*)d_in[3];
    const float* gt_boxes  = (const float*)d_in[4];
    const float* gt_ldm    = (const float*)d_in[5];
    float* out = (float*)d_out;

    float* sg3buf  = (float*)d_ws;                       // 2048 B
    int*   counter = (int*)((char*)d_ws + 2048);
    float* partial = (float*)((char*)d_ws + 2112);       // 4*16*469 floats

    prelude<<<1, 512, 0, stream>>>(gt_boxes, sg3buf, counter);
    dim3 grid(NBX, BN);
    loss_main<<<grid, BLK, 0, stream>>>(pred_cls, pred_bbox, pred_ldm, anchors,
                                        gt_boxes, gt_ldm, sg3buf, partial, counter, out);
}

// Round 9
// 219.943 us; speedup vs baseline: 1.8853x; 1.8774x over previous
//
#include <hip/hip_runtime.h>
#include <math.h>

#define AN 120000
#define BN 16
#define GN 32
#define BLK 256
#define NBX ((AN + BLK - 1) / BLK)   // 469
#define NBTOT (NBX * BN)             // 7504

typedef float f16v __attribute__((ext_vector_type(16)));

__device__ __forceinline__ float sl1(float d) {
    float ad = fabsf(d);
    return ad < 1.0f ? 0.5f * d * d : ad - 0.5f;
}

// ws layout: sg3buf [BN*GN] floats (2048 B) | partial [4][BN][NBX] @ 2048
__global__ __launch_bounds__(512) void prelude(const float* __restrict__ gt_boxes,
                                               float* __restrict__ sg3buf) {
    const int t = threadIdx.x;          // 512 = BN*GN
    float4 box = *(const float4*)(gt_boxes + t * 4);
    sg3buf[t] = (box.z - box.x) * (box.w - box.y) * (1.f / 3.f);
}

__global__ __launch_bounds__(256) void loss_main(
    const float* __restrict__ pred_cls,
    const float* __restrict__ pred_bbox,
    const float* __restrict__ pred_ldm,
    const float* __restrict__ anchors,
    const float* __restrict__ gt_boxes,
    const float* __restrict__ gt_ldm,
    const float* __restrict__ sg3buf,
    float* __restrict__ partial)        // [4][BN][NBX]
{
    __shared__ float4 gtb[GN];
    const int b   = blockIdx.y;
    const int tid = threadIdx.x;
    const int a   = blockIdx.x * BLK + tid;
    const bool val = (a < AN);

    if (tid < GN) gtb[tid] = *(const float4*)(gt_boxes + (b * GN + tid) * 4);

    // Anchor + pred_cls prefetch: VMEM latency overlaps the LDS fill.
    float4 an4 = make_float4(0.f, 0.f, 0.f, 0.f);
    if (val) an4 = *(const float4*)(anchors + (size_t)a * 4);
    float2 pc = make_float2(0.f, 0.f);
    if (val) pc = *(const float2*)(pred_cls + ((size_t)b * AN + a) * 2);

    const float sa3 = (an4.z - an4.x) * (an4.w - an4.y) * (1.f / 3.f);

    __syncthreads();

    // Per-g area/3 table -> SGPRs. Explicit s_load: wave-uniform by construction,
    // one-time ~200cy latency, keeps 32 b32 reads per row off the LDS pipe.
    const float* sg3p = sg3buf + b * GN;   // uniform address
    f16v sA, sB;
    asm volatile("s_load_dwordx16 %0, %2, 0x0\n\t"
                 "s_load_dwordx16 %1, %2, 0x40\n\t"
                 "s_waitcnt lgkmcnt(0)"
                 : "=&s"(sA), "=&s"(sB)
                 : "s"(sg3p));

    // Hot loop: per g = 1 ds_read_b128 (imm offset) + ~10 VALU.
    // Test: IoU>=0.5  <=>  inter >= (sa+sg)/3. Single clamp on iw suffices:
    // iw<=0 -> inter<=0 fails (rhs>0); iw>0,ih<0 -> inter<0 fails.
    bool pos = false;
#define IOUT(G, SG3) {                                                      \
        const float4 gb = gtb[(G)];                                         \
        float iw = fmaxf(fminf(an4.z, gb.z) - fmaxf(an4.x, gb.x), 0.f);     \
        float ih = fminf(an4.w, gb.w) - fmaxf(an4.y, gb.y);                 \
        pos = pos | (iw * ih >= sa3 + (SG3)); }
    #pragma unroll
    for (int g = 0; g < 16; ++g) IOUT(g, sA[g]);
    #pragma unroll
    for (int g = 0; g < 16; ++g) IOUT(g + 16, sB[g]);
#undef IOUT

    float ce = 0.f, np = 0.f, rl = 0.f, ll = 0.f;

    if (val) {
        // CE: stable lse = max + log(1 + exp(-|d|)), hardware exp/log.
        float d = pc.x - pc.y;
        float lse = fmaxf(pc.x, pc.y) + __logf(1.f + __expf(-fabsf(d)));
        ce = lse - (pos ? pc.y : pc.x);

        // Cold path (~0.03% of anchors). Boxes re-read from LDS.
        if (pos) {
            const float sa = (an4.z - an4.x) * (an4.w - an4.y);
            float bi = -1.f, bu = 1.f; int bg = 0;
            #pragma unroll 8
            for (int g = 0; g < GN; ++g) {
                float4 gb = gtb[g];
                float iw = fmaxf(fminf(an4.z, gb.z) - fmaxf(an4.x, gb.x), 0.f);
                float ih = fmaxf(fminf(an4.w, gb.w) - fmaxf(an4.y, gb.y), 0.f);
                float inter = iw * ih;
                float sg = (gb.z - gb.x) * (gb.w - gb.y);
                float uni = sa + sg - inter;
                bool upd = inter * bu > bi * uni;   // strict > keeps first max
                bi = upd ? inter : bi;
                bu = upd ? uni   : bu;
                bg = upd ? g     : bg;
            }
            np = 1.f;
            float4 gb = gtb[bg];
            float aw = an4.z - an4.x, ah = an4.w - an4.y;
            float acx = an4.x + 0.5f * aw, acy = an4.y + 0.5f * ah;
            float gw = gb.z - gb.x, gh = gb.w - gb.y;
            float gcx = gb.x + 0.5f * gw, gcy = gb.y + 0.5f * gh;
            float t0 = (gcx - acx) / aw;
            float t1 = (gcy - acy) / ah;
            float t2 = __logf(gw / aw);
            float t3 = __logf(gh / ah);
            const float4 pb = *(const float4*)(pred_bbox + ((size_t)b * AN + a) * 4);
            rl = sl1(pb.x - t0) + sl1(pb.y - t1) + sl1(pb.z - t2) + sl1(pb.w - t3);
            const float* pl = pred_ldm + ((size_t)b * AN + a) * 10;
            const float* gl = gt_ldm + ((size_t)b * GN + bg) * 10;
            float s = 0.f;
            #pragma unroll
            for (int j = 0; j < 10; ++j) s += sl1(pl[j] - gl[j]);
            ll = s;
        }
    }

    // Block reduction: wave shuffle then cross-wave via LDS. No atomics.
    __shared__ float red[4][4];
    #pragma unroll
    for (int off = 32; off > 0; off >>= 1) {
        ce += __shfl_down(ce, off, 64);
        np += __shfl_down(np, off, 64);
        rl += __shfl_down(rl, off, 64);
        ll += __shfl_down(ll, off, 64);
    }
    const int lane = tid & 63, wid = tid >> 6;
    if (lane == 0) { red[0][wid] = ce; red[1][wid] = np; red[2][wid] = rl; red[3][wid] = ll; }
    __syncthreads();
    if (tid < 4) {
        float s = red[tid][0] + red[tid][1] + red[tid][2] + red[tid][3];
        partial[(size_t)tid * (BN * NBX) + (size_t)b * NBX + blockIdx.x] = s;
    }
}

// Stage 2 (fused finalize, validated bit-exact in R2): 64 rows of NBX partials.
__global__ __launch_bounds__(256) void reduce_finalize(
    const float* __restrict__ partial, float* __restrict__ out)
{
    __shared__ float rowsum[64];
    const int tid = threadIdx.x;
    const int row = tid >> 2;          // 0..63 = q*16+b
    const int sub = tid & 3;

    float s = 0.f;
    const float* p = partial + (size_t)row * NBX;
    for (int j = sub; j < NBX; j += 4) s += p[j];
    s += __shfl_down(s, 1, 64);
    s += __shfl_down(s, 2, 64);
    if (sub == 0) rowsum[row] = s;
    __syncthreads();

    if (tid == 0) {
        float cls = 0.f, reg = 0.f, ldm = 0.f;
        for (int b = 0; b < BN; ++b) {
            cls += rowsum[0 * BN + b] / (float)AN;
            float npv = rowsum[1 * BN + b];
            float den = fmaxf(npv, 1.f);
            bool has = npv > 0.f;
            reg += has ? rowsum[2 * BN + b] / (den * 4.f)  : 0.f;
            ldm += has ? rowsum[3 * BN + b] / (den * 10.f) : 0.f;
        }
        cls /= (float)BN; reg /= (float)BN; ldm /= (float)BN;
        out[0] = cls + reg + ldm;
        out[1] = cls;
        out[2] = reg;
        out[3] = ldm;
    }
}

extern "C" void kernel_launch(void* const* d_in, const int* in_sizes, int n_in,
                              void* d_out, int out_size, void* d_ws, size_t ws_size,
                              hipStream_t stream) {
    const float* pred_cls  = (const float*)d_in[0];
    const float* pred_bbox = (const float*)d_in[1];
    const float* pred_ldm  = (const float*)d_in[2];
    const float* anchors   = (const float*)d_in[3];
    const float* gt_boxes  = (const float*)d_in[4];
    const float* gt_ldm    = (const float*)d_in[5];
    float* out = (float*)d_out;

    float* sg3buf  = (float*)d_ws;                  // 2048 B
    float* partial = (float*)((char*)d_ws + 2048);  // 4*16*469 floats

    prelude<<<1, 512, 0, stream>>>(gt_boxes, sg3buf);
    dim3 grid(NBX, BN);
    loss_main<<<grid, BLK, 0, stream>>>(pred_cls, pred_bbox, pred_ldm, anchors,
                                        gt_boxes, gt_ldm, sg3buf, partial);
    reduce_finalize<<<1, 256, 0, stream>>>(partial, out);
}

// Round 10
// 209.044 us; speedup vs baseline: 1.9836x; 1.0521x over previous
//
#include <hip/hip_runtime.h>
#include <math.h>

#define AN 120000
#define BN 16
#define GN 32
#define BLK 256
#define TPB 4                          // tiles (of 256 anchors) per block, sequential
#define TILE (BLK * TPB)               // 1024 anchors per block
#define NBX ((AN + TILE - 1) / TILE)   // 118 blocks along anchors

typedef float f16v __attribute__((ext_vector_type(16)));

__device__ __forceinline__ float sl1(float d) {
    float ad = fabsf(d);
    return ad < 1.0f ? 0.5f * d * d : ad - 0.5f;
}

// ws layout: sg3buf [BN*GN] floats (2048 B) | partial [4][BN][NBX] @ 2048
__global__ __launch_bounds__(512) void prelude(const float* __restrict__ gt_boxes,
                                               float* __restrict__ sg3buf) {
    const int t = threadIdx.x;          // 512 = BN*GN
    float4 box = *(const float4*)(gt_boxes + t * 4);
    sg3buf[t] = (box.z - box.x) * (box.w - box.y) * (1.f / 3.f);
}

__global__ __launch_bounds__(256) void loss_main(
    const float* __restrict__ pred_cls,
    const float* __restrict__ pred_bbox,
    const float* __restrict__ pred_ldm,
    const float* __restrict__ anchors,
    const float* __restrict__ gt_boxes,
    const float* __restrict__ gt_ldm,
    const float* __restrict__ sg3buf,
    float* __restrict__ partial)        // [4][BN][NBX]
{
    __shared__ float4 gtb[GN];
    const int b   = blockIdx.y;
    const int tid = threadIdx.x;
    const int base = blockIdx.x * TILE + tid;

    if (tid < GN) gtb[tid] = *(const float4*)(gt_boxes + (b * GN + tid) * 4);

    // Tile 0 prefetch: VMEM latency overlaps LDS fill + s_load.
    int a0 = base;
    bool val0 = (a0 < AN);
    float4 an_cur = make_float4(0.f, 0.f, 0.f, 0.f);
    float2 pc_cur = make_float2(0.f, 0.f);
    if (val0) {
        an_cur = *(const float4*)(anchors + (size_t)a0 * 4);
        pc_cur = *(const float2*)(pred_cls + ((size_t)b * AN + a0) * 2);
    }

    __syncthreads();

    // Per-g area/3 table -> SGPRs (once per block, reused across 4 tiles).
    const float* sg3p = sg3buf + b * GN;
    f16v sA, sB;
    asm volatile("s_load_dwordx16 %0, %2, 0x0\n\t"
                 "s_load_dwordx16 %1, %2, 0x40\n\t"
                 "s_waitcnt lgkmcnt(0)"
                 : "=&s"(sA), "=&s"(sB)
                 : "s"(sg3p));

    float ce = 0.f, np = 0.f, rl = 0.f, ll = 0.f;

    // Sequential tile loop: per-block fixed costs amortized over 4 tiles.
    #pragma unroll
    for (int t = 0; t < TPB; ++t) {
        const int a = base + t * BLK;
        const bool val = (a < AN);
        const float4 an4 = an_cur;
        const float2 pc  = pc_cur;

        // Depth-2 software pipeline: issue next tile's loads before computing.
        if (t + 1 < TPB) {
            const int an_ = base + (t + 1) * BLK;
            if (an_ < AN) {
                an_cur = *(const float4*)(anchors + (size_t)an_ * 4);
                pc_cur = *(const float2*)(pred_cls + ((size_t)b * AN + an_) * 2);
            } else {
                an_cur = make_float4(0.f, 0.f, 0.f, 0.f);
                pc_cur = make_float2(0.f, 0.f);
            }
        }

        const float sa3 = (an4.z - an4.x) * (an4.w - an4.y) * (1.f / 3.f);

        // Hot loop: per g = 1 ds_read_b128 (imm offset, broadcast) + ~10 VALU.
        // Test: IoU>=0.5  <=>  inter >= (sa+sg)/3. Single clamp on iw suffices.
        bool pos = false;
#define IOUT(G, SG3) {                                                      \
        const float4 gb = gtb[(G)];                                         \
        float iw = fmaxf(fminf(an4.z, gb.z) - fmaxf(an4.x, gb.x), 0.f);     \
        float ih = fminf(an4.w, gb.w) - fmaxf(an4.y, gb.y);                 \
        pos = pos | (iw * ih >= sa3 + (SG3)); }
        #pragma unroll
        for (int g = 0; g < 16; ++g) IOUT(g, sA[g]);
        #pragma unroll
        for (int g = 0; g < 16; ++g) IOUT(g + 16, sB[g]);
#undef IOUT

        if (val) {
            // CE: stable lse = max + log(1 + exp(-|d|)), hardware exp/log.
            float d = pc.x - pc.y;
            float lse = fmaxf(pc.x, pc.y) + __logf(1.f + __expf(-fabsf(d)));
            ce += lse - (pos ? pc.y : pc.x);

            // Cold path (~0.03% of anchors). Boxes re-read from LDS.
            if (pos) {
                const float sa = (an4.z - an4.x) * (an4.w - an4.y);
                float bi = -1.f, bu = 1.f; int bg = 0;
                #pragma unroll 8
                for (int g = 0; g < GN; ++g) {
                    float4 gb = gtb[g];
                    float iw = fmaxf(fminf(an4.z, gb.z) - fmaxf(an4.x, gb.x), 0.f);
                    float ih = fmaxf(fminf(an4.w, gb.w) - fmaxf(an4.y, gb.y), 0.f);
                    float inter = iw * ih;
                    float sg = (gb.z - gb.x) * (gb.w - gb.y);
                    float uni = sa + sg - inter;
                    bool upd = inter * bu > bi * uni;   // strict > keeps first max
                    bi = upd ? inter : bi;
                    bu = upd ? uni   : bu;
                    bg = upd ? g     : bg;
                }
                np += 1.f;
                float4 gb = gtb[bg];
                float aw = an4.z - an4.x, ah = an4.w - an4.y;
                float acx = an4.x + 0.5f * aw, acy = an4.y + 0.5f * ah;
                float gw = gb.z - gb.x, gh = gb.w - gb.y;
                float gcx = gb.x + 0.5f * gw, gcy = gb.y + 0.5f * gh;
                float t0 = (gcx - acx) / aw;
                float t1 = (gcy - acy) / ah;
                float t2 = __logf(gw / aw);
                float t3 = __logf(gh / ah);
                const float4 pb = *(const float4*)(pred_bbox + ((size_t)b * AN + a) * 4);
                rl += sl1(pb.x - t0) + sl1(pb.y - t1) + sl1(pb.z - t2) + sl1(pb.w - t3);
                const float* pl = pred_ldm + ((size_t)b * AN + a) * 10;
                const float* gl = gt_ldm + ((size_t)b * GN + bg) * 10;
                float s = 0.f;
                #pragma unroll
                for (int j = 0; j < 10; ++j) s += sl1(pl[j] - gl[j]);
                ll += s;
            }
        }
    }

    // Block reduction (once per 1024 anchors): wave shuffle then cross-wave LDS.
    __shared__ float red[4][4];
    #pragma unroll
    for (int off = 32; off > 0; off >>= 1) {
        ce += __shfl_down(ce, off, 64);
        np += __shfl_down(np, off, 64);
        rl += __shfl_down(rl, off, 64);
        ll += __shfl_down(ll, off, 64);
    }
    const int lane = tid & 63, wid = tid >> 6;
    if (lane == 0) { red[0][wid] = ce; red[1][wid] = np; red[2][wid] = rl; red[3][wid] = ll; }
    __syncthreads();
    if (tid < 4) {
        float s = red[tid][0] + red[tid][1] + red[tid][2] + red[tid][3];
        partial[(size_t)tid * (BN * NBX) + (size_t)b * NBX + blockIdx.x] = s;
    }
}

// Stage 2 (fused finalize, validated bit-exact in R2 with NBX=118).
__global__ __launch_bounds__(256) void reduce_finalize(
    const float* __restrict__ partial, float* __restrict__ out)
{
    __shared__ float rowsum[64];
    const int tid = threadIdx.x;
    const int row = tid >> 2;          // 0..63 = q*16+b
    const int sub = tid & 3;

    float s = 0.f;
    const float* p = partial + (size_t)row * NBX;
    for (int j = sub; j < NBX; j += 4) s += p[j];
    s += __shfl_down(s, 1, 64);
    s += __shfl_down(s, 2, 64);
    if (sub == 0) rowsum[row] = s;
    __syncthreads();

    if (tid == 0) {
        float cls = 0.f, reg = 0.f, ldm = 0.f;
        for (int b = 0; b < BN; ++b) {
            cls += rowsum[0 * BN + b] / (float)AN;
            float npv = rowsum[1 * BN + b];
            float den = fmaxf(npv, 1.f);
            bool has = npv > 0.f;
            reg += has ? rowsum[2 * BN + b] / (den * 4.f)  : 0.f;
            ldm += has ? rowsum[3 * BN + b] / (den * 10.f) : 0.f;
        }
        cls /= (float)BN; reg /= (float)BN; ldm /= (float)BN;
        out[0] = cls + reg + ldm;
        out[1] = cls;
        out[2] = reg;
        out[3] = ldm;
    }
}

extern "C" void kernel_launch(void* const* d_in, const int* in_sizes, int n_in,
                              void* d_out, int out_size, void* d_ws, size_t ws_size,
                              hipStream_t stream) {
    const float* pred_cls  = (const float*)d_in[0];
    const float* pred_bbox = (const float*)d_in[1];
    const float* pred_ldm  = (const float*)d_in[2];
    const float* anchors   = (const float*)d_in[3];
    const float* gt_boxes  = (const float*)d_in[4];
    const float* gt_ldm    = (const float*)d_in[5];
    float* out = (float*)d_out;

    float* sg3buf  = (float*)d_ws;                  // 2048 B
    float* partial = (float*)((char*)d_ws + 2048);  // 4*16*118 floats

    prelude<<<1, 512, 0, stream>>>(gt_boxes, sg3buf);
    dim3 grid(NBX, BN);
    loss_main<<<grid, BLK, 0, stream>>>(pred_cls, pred_bbox, pred_ldm, anchors,
                                        gt_boxes, gt_ldm, sg3buf, partial);
    reduce_finalize<<<1, 256, 0, stream>>>(partial, out);
}